// Round 3
// baseline (1331.455 us; speedup 1.0000x reference)
//
#include <hip/hip_runtime.h>
#include <cstdint>
#include <cstddef>

// ---------------------------------------------------------------- types
typedef __bf16 bf16_t;
typedef __bf16 bf16x8 __attribute__((ext_vector_type(8)));
typedef __bf16 bf16x4 __attribute__((ext_vector_type(4)));
typedef float  f32x4  __attribute__((ext_vector_type(4)));
typedef short  s16x4  __attribute__((ext_vector_type(4)));

#define DEV __device__ __forceinline__

static constexpr int   BATCH = 2;
static constexpr int   NTOK  = 1024;
static constexpr int   DIM   = 1024;
static constexpr int   MROWS = BATCH * NTOK;      // 2048 token rows
static constexpr float SCALE = 0.125f;            // 64^-0.5 (exact in bf16)

// ------------------------------------------------------- global->LDS DMA
DEV void load_lds16(const bf16_t* g, bf16_t* s) {
  __builtin_amdgcn_global_load_lds(
      (const __attribute__((address_space(1))) void*)g,
      (__attribute__((address_space(3))) void*)s, 16, 0, 0);
}

// ------------------------------------------------------------ reductions
DEV float wave_sum(float v) {
#pragma unroll
  for (int m = 1; m < 64; m <<= 1) v += __shfl_xor(v, m, 64);
  return v;
}
DEV float block_sum(float v, float* sb) {
  v = wave_sum(v);
  __syncthreads();
  if ((threadIdx.x & 63) == 0) sb[threadIdx.x >> 6] = v;
  __syncthreads();
  return sb[0] + sb[1] + sb[2] + sb[3];
}

// ------------------------------------------------------------------ GEMM
// C[M,N] = A[M,K] @ B[K,N], with B given transposed: BT[N][K] (row-major).
// Fragment layout (verified):
//   A frag:  A[m = lane&15][k = (lane>>4)*8 + j]   -> 8 contiguous bf16
//   B frag:  BT[n = lane&15][k = (lane>>4)*8 + j]  -> 8 contiguous bf16
//   C/D:     col = lane&15, row = (lane>>4)*4 + reg
// Batch/split via blockIdx.z: off = (z>>4)*s0 + (z&15)*s1.
// MODE 0: C(bf16) = acc * (col<1024 ? alpha : 1)        [qkv, q pre-scale]
// MODE 1: C(bf16) = acc + bias[col]
// MODE 2: atomicAdd(C(f32), (acc + bias?)*ls[col])      [split-K residual;
//         bias applied only on the last z-slice]
template <int BM, int BN, int WR, int WC, int MODE>
__global__ __launch_bounds__(256) void gemm_bt(
    const bf16_t* __restrict__ A, long sA0, long sA1, int lda,
    const bf16_t* __restrict__ B, long sB0, long sB1, int ldb,
    void* __restrict__ Cv, long sC0, long sC1, int ldc,
    int K, float alpha, const float* __restrict__ bias,
    const float* __restrict__ ls) {
  constexpr int TM = BM / WR / 16;
  constexpr int TN = BN / WC / 16;
  __shared__ __attribute__((aligned(16))) bf16_t As[BM * 32];
  __shared__ __attribute__((aligned(16))) bf16_t Bs[BN * 32];

  const int tid  = threadIdx.x;
  const int lane = tid & 63, wave = tid >> 6;
  const int z  = blockIdx.z;
  const int zh = z >> 4, zl = z & 15;
  A += (size_t)zh * sA0 + (size_t)zl * sA1;
  B += (size_t)zh * sB0 + (size_t)zl * sB1;

  const int m0 = blockIdx.y * BM, n0 = blockIdx.x * BN;
  const int wm = (wave / WC) * (BM / WR);
  const int wn = (wave % WC) * (BN / WC);
  const int fm = lane & 15, quad = lane >> 4;

  f32x4 acc[TM][TN] = {};

  for (int k0 = 0; k0 < K; k0 += 32) {
#pragma unroll
    for (int c = tid; c < BM * 4; c += 256) {
      const int row = c >> 2, kc = (c & 3) << 3;
      load_lds16(A + (size_t)(m0 + row) * lda + k0 + kc, &As[c * 8]);
    }
#pragma unroll
    for (int c = tid; c < BN * 4; c += 256) {
      const int row = c >> 2, kc = (c & 3) << 3;
      load_lds16(B + (size_t)(n0 + row) * ldb + k0 + kc, &Bs[c * 8]);
    }
    __syncthreads();

    bf16x8 af[TM], bfr[TN];
#pragma unroll
    for (int i = 0; i < TM; ++i)
      af[i] = *(const bf16x8*)&As[(wm + i * 16 + fm) * 32 + quad * 8];
#pragma unroll
    for (int j = 0; j < TN; ++j)
      bfr[j] = *(const bf16x8*)&Bs[(wn + j * 16 + fm) * 32 + quad * 8];
#pragma unroll
    for (int i = 0; i < TM; ++i)
#pragma unroll
      for (int j = 0; j < TN; ++j)
        acc[i][j] = __builtin_amdgcn_mfma_f32_16x16x32_bf16(af[i], bfr[j],
                                                            acc[i][j], 0, 0, 0);
    __syncthreads();
  }

  const size_t coff = (size_t)zh * sC0 + (size_t)zl * sC1;
  const bool last_z = (zl + 1 == (int)gridDim.z);
#pragma unroll
  for (int i = 0; i < TM; ++i) {
#pragma unroll
    for (int j = 0; j < TN; ++j) {
      const int col  = n0 + wn + j * 16 + fm;
      const int rowb = m0 + wm + i * 16 + quad * 4;
#pragma unroll
      for (int r = 0; r < 4; ++r) {
        const float  v   = acc[i][j][r];
        const size_t idx = coff + (size_t)(rowb + r) * ldc + col;
        if constexpr (MODE == 0) {
          ((bf16_t*)Cv)[idx] = (bf16_t)(col < 1024 ? v * alpha : v);
        } else if constexpr (MODE == 1) {
          ((bf16_t*)Cv)[idx] = (bf16_t)(v + bias[col]);
        } else {
          const float bb = (bias && last_z) ? bias[col] : 0.f;
          atomicAdd(&((float*)Cv)[idx], (v + bb) * ls[col]);
        }
      }
    }
  }
}

// ---------------------------------------------- fused ff1 + GEGLU GEMM
// ff[M,4096] = (h @ Wa + ba) * gelu(h @ Wg + bg)
// Wa = wff1T rows [0,4096), Wg = rows [4096,8192) (BT layout [8192][1024]).
// grid (4096/BN, M/BM); each block computes matching a- and g-tiles.
template <int BM, int BN>
__global__ __launch_bounds__(256) void gemm_ff1_geglu(
    const bf16_t* __restrict__ A, int lda,
    const bf16_t* __restrict__ BT,           // [8192][1024]
    bf16_t* __restrict__ ff,                 // [M][4096]
    const float* __restrict__ bias,          // [8192]
    int K) {
  constexpr int WR = 2, WC = 2;
  constexpr int TM = BM / WR / 16;           // 4
  constexpr int TN = BN / WC / 16;           // 4
  __shared__ __attribute__((aligned(16))) bf16_t As[BM * 32];
  __shared__ __attribute__((aligned(16))) bf16_t Bas[BN * 32];
  __shared__ __attribute__((aligned(16))) bf16_t Bgs[BN * 32];

  const int tid  = threadIdx.x;
  const int lane = tid & 63, wave = tid >> 6;
  const int m0 = blockIdx.y * BM, n0 = blockIdx.x * BN;
  const int wm = (wave / WC) * (BM / WR);
  const int wn = (wave % WC) * (BN / WC);
  const int fm = lane & 15, quad = lane >> 4;

  const bf16_t* Ba = BT + (size_t)n0 * K;
  const bf16_t* Bg = BT + (size_t)(n0 + 4096) * K;

  f32x4 acca[TM][TN] = {}, accg[TM][TN] = {};

  for (int k0 = 0; k0 < K; k0 += 32) {
#pragma unroll
    for (int c = tid; c < BM * 4; c += 256) {
      const int row = c >> 2, kc = (c & 3) << 3;
      load_lds16(A + (size_t)(m0 + row) * lda + k0 + kc, &As[c * 8]);
    }
#pragma unroll
    for (int c = tid; c < BN * 4; c += 256) {
      const int row = c >> 2, kc = (c & 3) << 3;
      load_lds16(Ba + (size_t)row * K + k0 + kc, &Bas[c * 8]);
      load_lds16(Bg + (size_t)row * K + k0 + kc, &Bgs[c * 8]);
    }
    __syncthreads();

    bf16x8 af[TM], ba[TN], bg[TN];
#pragma unroll
    for (int i = 0; i < TM; ++i)
      af[i] = *(const bf16x8*)&As[(wm + i * 16 + fm) * 32 + quad * 8];
#pragma unroll
    for (int j = 0; j < TN; ++j) {
      ba[j] = *(const bf16x8*)&Bas[(wn + j * 16 + fm) * 32 + quad * 8];
      bg[j] = *(const bf16x8*)&Bgs[(wn + j * 16 + fm) * 32 + quad * 8];
    }
#pragma unroll
    for (int i = 0; i < TM; ++i)
#pragma unroll
      for (int j = 0; j < TN; ++j) {
        acca[i][j] = __builtin_amdgcn_mfma_f32_16x16x32_bf16(af[i], ba[j],
                                                             acca[i][j], 0, 0, 0);
        accg[i][j] = __builtin_amdgcn_mfma_f32_16x16x32_bf16(af[i], bg[j],
                                                             accg[i][j], 0, 0, 0);
      }
    __syncthreads();
  }

#pragma unroll
  for (int i = 0; i < TM; ++i) {
#pragma unroll
    for (int j = 0; j < TN; ++j) {
      const int col  = n0 + wn + j * 16 + fm;
      const int rowb = m0 + wm + i * 16 + quad * 4;
      const float ab = bias[col], gb = bias[col + 4096];
#pragma unroll
      for (int r = 0; r < 4; ++r) {
        const float a  = acca[i][j][r] + ab;
        const float g  = accg[i][j][r] + gb;
        const float ge = 0.5f * g * (1.f + erff(g * 0.70710678118654752f));
        ff[(size_t)(rowb + r) * 4096 + col] = (bf16_t)(a * ge);
      }
    }
  }
}

// --------------------------------------------------------- flash attention
// One block per (64-row Q tile, z = b*16+h). 4 waves, each owning 16 Q rows.
// Computes S^T = K @ Q^T (operand-swapped MFMA): C-layout gives
// col = query (lane&15), row = key token (quad*4+reg). That register layout
// IS the A-fragment layout of mfma_f32_16x16x16bf16_1k (K=16), so P feeds
// P@V directly from registers — no LDS round-trip for P.
// Q is pre-scaled by SCALE in the qkv GEMM epilogue.
__global__ __launch_bounds__(256) void flash_attn(
    const bf16_t* __restrict__ qkv,   // [2][1024][3072] (q cols pre-scaled)
    const bf16_t* __restrict__ vT,    // [32][64][1024]
    bf16_t* __restrict__ o) {         // [2][1024][1024] col = h*64+d
  constexpr int NT = 128;
  __shared__ __attribute__((aligned(16))) bf16_t Qs[2 * 64 * 32];   // 8 KB
  __shared__ __attribute__((aligned(16))) bf16_t Ks[2 * NT * 32];   // 16 KB
  __shared__ __attribute__((aligned(16))) bf16_t Vs[4 * 64 * 32];   // 16 KB

  const int tid = threadIdx.x, lane = tid & 63, wave = tid >> 6;
  const int fm = lane & 15, quad = lane >> 4;
  const int z = blockIdx.y, b = z >> 4, h = z & 15;
  const int q0 = blockIdx.x * 64;
  const bf16_t* qb  = qkv + (size_t)b * 1024 * 3072 + h * 64;
  const bf16_t* kb  = qb + 1024;
  const bf16_t* vtb = vT + (size_t)z * 64 * 1024;

  // stage Q tile: layout [kk(2)][row(64)][32]
  for (int c = tid; c < 512; c += 256) {
    const int kk = c >> 8, rr = (c >> 2) & 63, ii = c & 3;
    load_lds16(qb + (size_t)(q0 + rr) * 3072 + kk * 32 + ii * 8, &Qs[c * 8]);
  }
  __syncthreads();
  bf16x8 qf[2];
  qf[0] = *(const bf16x8*)&Qs[(wave * 16 + fm) * 32 + quad * 8];
  qf[1] = *(const bf16x8*)&Qs[64 * 32 + (wave * 16 + fm) * 32 + quad * 8];

  float mr = -1e30f, lr = 0.f;
  f32x4 oacc[4] = {};

  for (int kv0 = 0; kv0 < 1024; kv0 += NT) {
    __syncthreads();  // all waves done reading previous K/V tiles
    // K tile [kk(2)][tok(128)][32]
    for (int c = tid; c < NT * 8; c += 256) {
      const int kk = c >> 9, rr = (c >> 2) & 127, ii = c & 3;
      load_lds16(kb + (size_t)(kv0 + rr) * 3072 + kk * 32 + ii * 8, &Ks[c * 8]);
    }
    // V^T tile [tc(4)][d(64)][32]
    for (int c = tid; c < 1024; c += 256) {
      const int tc = c >> 8, rr = (c >> 2) & 63, ii = c & 3;
      load_lds16(vtb + (size_t)rr * 1024 + kv0 + tc * 32 + ii * 8, &Vs[c * 8]);
    }
    __syncthreads();

    // S^T tiles: st[nt] holds S[query = lane&15][j = nt*16 + quad*4 + r]
    f32x4 st[8];
#pragma unroll
    for (int nt = 0; nt < 8; ++nt) {
      st[nt] = (f32x4){0.f, 0.f, 0.f, 0.f};
#pragma unroll
      for (int kk = 0; kk < 2; ++kk) {
        const bf16x8 kf =
            *(const bf16x8*)&Ks[kk * NT * 32 + (nt * 16 + fm) * 32 + quad * 8];
        st[nt] = __builtin_amdgcn_mfma_f32_16x16x32_bf16(kf, qf[kk], st[nt],
                                                         0, 0, 0);
      }
    }
    // online softmax: this lane owns one query row (lane&15), 32 j's;
    // full row spread across the 4 quads -> xor-16/32 reductions.
    float mx = st[0][0];
#pragma unroll
    for (int nt = 0; nt < 8; ++nt)
#pragma unroll
      for (int r = 0; r < 4; ++r) mx = fmaxf(mx, st[nt][r]);
    mx = fmaxf(mx, __shfl_xor(mx, 16, 64));
    mx = fmaxf(mx, __shfl_xor(mx, 32, 64));
    const float mn = fmaxf(mr, mx);
    const float al = __expf(mr - mn);
    mr = mn;
    float ps = 0.f;
    s16x4 pf[8];
#pragma unroll
    for (int nt = 0; nt < 8; ++nt) {
      bf16x4 pv;
#pragma unroll
      for (int r = 0; r < 4; ++r) {
        const float p = __expf(st[nt][r] - mn);
        ps += p;
        pv[r] = (bf16_t)p;
      }
      pf[nt] = __builtin_bit_cast(s16x4, pv);
    }
    ps += __shfl_xor(ps, 16, 64);
    ps += __shfl_xor(ps, 32, 64);
    lr = lr * al + ps;
    // rescale O: O rows are quad*4+r -> fetch that row's alpha via shuffle
    float alr[4];
#pragma unroll
    for (int r = 0; r < 4; ++r) alr[r] = __shfl(al, quad * 4 + r, 64);
#pragma unroll
    for (int t = 0; t < 4; ++t)
#pragma unroll
      for (int r = 0; r < 4; ++r) oacc[t][r] *= alr[r];
    // O += P @ V  (K=16 MFMA; P straight from registers)
#pragma unroll
    for (int nt = 0; nt < 8; ++nt) {
      const int tok = nt * 16 + quad * 4;
      const int tc = tok >> 5, tin = tok & 31;
#pragma unroll
      for (int t = 0; t < 4; ++t) {
        const bf16x4 vv =
            *(const bf16x4*)&Vs[tc * 2048 + (t * 16 + fm) * 32 + tin];
        oacc[t] = __builtin_amdgcn_mfma_f32_16x16x16bf16_1k(
            pf[nt], __builtin_bit_cast(s16x4, vv), oacc[t], 0, 0, 0);
      }
    }
  }

  // epilogue: normalize and store (C layout: row = quad*4+r, col = t*16+fm)
  float linv[4];
#pragma unroll
  for (int r = 0; r < 4; ++r) linv[r] = 1.f / __shfl(lr, quad * 4 + r, 64);
  const size_t orow0 = (size_t)b * 1024 + q0 + wave * 16 + quad * 4;
#pragma unroll
  for (int t = 0; t < 4; ++t) {
    const int col = h * 64 + t * 16 + fm;
#pragma unroll
    for (int r = 0; r < 4; ++r)
      o[(orow0 + r) * 1024 + col] = (bf16_t)(oacc[t][r] * linv[r]);
  }
}

// ------------------------------------------------- weight transpose+cast
// W[K][N] fp32 -> WT[N][K] bf16, all DEPTH layers via blockIdx.z.
__global__ __launch_bounds__(256) void transpose_w(const float* __restrict__ W,
                                                   bf16_t* __restrict__ WT,
                                                   int K, int N) {
  __shared__ float t[32][33];
  W  += (size_t)blockIdx.z * K * N;
  WT += (size_t)blockIdx.z * K * N;
  const int n0 = blockIdx.x * 32, k0 = blockIdx.y * 32;
  const int tx = threadIdx.x & 31, ty = threadIdx.x >> 5;
#pragma unroll
  for (int s = 0; s < 4; ++s)
    t[ty + 8 * s][tx] = W[(size_t)(k0 + ty + 8 * s) * N + n0 + tx];
  __syncthreads();
#pragma unroll
  for (int s = 0; s < 4; ++s)
    WT[(size_t)(n0 + ty + 8 * s) * K + k0 + tx] = (bf16_t)t[tx][ty + 8 * s];
}

// ----------------------------------------------------- V transpose (bf16)
// qkv[b*1024+tok][2048 + h*64 + d] -> vT[z=b*16+h][d][tok]
__global__ __launch_bounds__(256) void transpose_v(const bf16_t* __restrict__ qkv,
                                                   bf16_t* __restrict__ vT) {
  __shared__ bf16_t t[32][33];
  const int z = blockIdx.z, b = z >> 4, h = z & 15;
  const int d0 = blockIdx.y * 32, n0 = blockIdx.x * 32;
  const int tx = threadIdx.x & 31, ty = threadIdx.x >> 5;
  const bf16_t* src = qkv + (size_t)b * NTOK * 3072 + 2048 + h * 64;
#pragma unroll
  for (int s = 0; s < 4; ++s)
    t[ty + 8 * s][tx] = src[(size_t)(n0 + ty + 8 * s) * 3072 + d0 + tx];
  __syncthreads();
  bf16_t* dst = vT + (size_t)z * 64 * NTOK;
#pragma unroll
  for (int s = 0; s < 4; ++s)
    dst[(size_t)(d0 + ty + 8 * s) * NTOK + n0 + tx] = t[tx][ty + 8 * s];
}

// -------------------------------------------------------------- layernorm
__global__ __launch_bounds__(256) void ln_kernel(const float* __restrict__ x,
                                                 const float* __restrict__ w,
                                                 const float* __restrict__ b,
                                                 bf16_t* __restrict__ out) {
  __shared__ float sb[4];
  const int row = blockIdx.x, tid = threadIdx.x;
  const float4 v = ((const float4*)(x + (size_t)row * DIM))[tid];
  float s = v.x + v.y + v.z + v.w;
  s = block_sum(s, sb);
  const float mu = s * (1.f / DIM);
  const float dx = v.x - mu, dy = v.y - mu, dz = v.z - mu, dw = v.w - mu;
  float q = dx * dx + dy * dy + dz * dz + dw * dw;
  q = block_sum(q, sb);
  const float rstd = rsqrtf(q * (1.f / DIM) + 1e-5f);
  const float4 wv = ((const float4*)w)[tid];
  const float4 bv = ((const float4*)b)[tid];
  bf16x4 o;
  o[0] = (bf16_t)(dx * rstd * wv.x + bv.x);
  o[1] = (bf16_t)(dy * rstd * wv.y + bv.y);
  o[2] = (bf16_t)(dz * rstd * wv.z + bv.z);
  o[3] = (bf16_t)(dw * rstd * wv.w + bv.w);
  ((bf16x4*)(out + (size_t)row * DIM))[tid] = o;
}

// ------------------------------------------------------------------ launch
extern "C" void kernel_launch(void* const* d_in, const int* in_sizes, int n_in,
                              void* d_out, int out_size, void* d_ws,
                              size_t ws_size, hipStream_t stream) {
  const float* x_in = (const float*)d_in[0];
  const float* ln1w = (const float*)d_in[1];
  const float* ln1b = (const float*)d_in[2];
  const float* wqkv = (const float*)d_in[3];
  const float* wout = (const float*)d_in[4];
  const float* bout = (const float*)d_in[5];
  const float* ls1  = (const float*)d_in[6];
  const float* ln2w = (const float*)d_in[7];
  const float* ln2b = (const float*)d_in[8];
  const float* wff1 = (const float*)d_in[9];
  const float* bff1 = (const float*)d_in[10];
  const float* wff2 = (const float*)d_in[11];
  const float* bff2 = (const float*)d_in[12];
  const float* ls2  = (const float*)d_in[13];
  float*       xout = (float*)d_out;

  // -------- workspace carve-up (~176 MB)
  char*   ws     = (char*)d_ws;
  bf16_t* wqkvT  = (bf16_t*)ws; ws += (size_t)4 * 3072 * 1024 * 2;  // 25.2 MB
  bf16_t* woutT  = (bf16_t*)ws; ws += (size_t)4 * 1024 * 1024 * 2;  //  8.4 MB
  bf16_t* wff1T  = (bf16_t*)ws; ws += (size_t)4 * 8192 * 1024 * 2;  // 67.1 MB
  bf16_t* wff2T  = (bf16_t*)ws; ws += (size_t)4 * 1024 * 4096 * 2;  // 33.6 MB
  bf16_t* h_bf   = (bf16_t*)ws; ws += (size_t)MROWS * 1024 * 2;     //  4.2 MB
  bf16_t* qkv_bf = (bf16_t*)ws; ws += (size_t)MROWS * 3072 * 2;     // 12.6 MB
  bf16_t* o_bf   = (bf16_t*)ws; ws += (size_t)MROWS * 1024 * 2;     //  4.2 MB
  bf16_t* vT     = (bf16_t*)ws; ws += (size_t)32 * 64 * 1024 * 2;   //  4.2 MB
  bf16_t* ff_bf  = (bf16_t*)ws; ws += (size_t)MROWS * 4096 * 2;     // 16.8 MB
  if (ws_size < (size_t)(ws - (char*)d_ws)) return;  // visible fail

  hipMemcpyAsync(xout, x_in, (size_t)MROWS * DIM * 4,
                 hipMemcpyDeviceToDevice, stream);

  // ---- all weight transposes up front (all 4 layers per launch)
  transpose_w<<<dim3(96, 32, 4), 256, 0, stream>>>(wqkv, wqkvT, 1024, 3072);
  transpose_w<<<dim3(32, 32, 4), 256, 0, stream>>>(wout, woutT, 1024, 1024);
  transpose_w<<<dim3(256, 32, 4), 256, 0, stream>>>(wff1, wff1T, 1024, 8192);
  transpose_w<<<dim3(32, 128, 4), 256, 0, stream>>>(wff2, wff2T, 4096, 1024);

  for (int l = 0; l < 4; ++l) {
    const bf16_t* wqkvTl = wqkvT + (size_t)l * 3072 * 1024;
    const bf16_t* woutTl = woutT + (size_t)l * 1024 * 1024;
    const bf16_t* wff1Tl = wff1T + (size_t)l * 8192 * 1024;
    const bf16_t* wff2Tl = wff2T + (size_t)l * 4096 * 1024;

    // ---- attention
    ln_kernel<<<MROWS, 256, 0, stream>>>(xout, ln1w + l * 1024,
                                         ln1b + l * 1024, h_bf);
    // qkv = h @ wqkv ; q columns pre-scaled by SCALE. 768 blocks (3/CU).
    gemm_bt<64, 128, 1, 4, 0><<<dim3(24, 32, 1), 256, 0, stream>>>(
        h_bf, 0, 0, 1024, wqkvTl, 0, 0, 1024, qkv_bf, 0, 0, 3072, 1024,
        SCALE, nullptr, nullptr);
    transpose_v<<<dim3(32, 2, 32), 256, 0, stream>>>(qkv_bf, vT);
    flash_attn<<<dim3(16, 32), 256, 0, stream>>>(qkv_bf, vT, o_bf);
    // x += (o @ w_out + b_out) * ls1 ; split-K x2 atomic (512 blocks)
    gemm_bt<64, 128, 1, 4, 2><<<dim3(8, 32, 2), 256, 0, stream>>>(
        o_bf, 0, 512, 1024, woutTl, 0, 512, 1024, xout, 0, 0, 1024, 512,
        1.f, bout + l * 1024, ls1 + l * 1024);

    // ---- feedforward
    ln_kernel<<<MROWS, 256, 0, stream>>>(xout, ln2w + l * 1024,
                                         ln2b + l * 1024, h_bf);
    // fused ff1 + geglu (512 blocks)
    gemm_ff1_geglu<128, 128><<<dim3(32, 16), 256, 0, stream>>>(
        h_bf, 1024, wff1Tl, ff_bf, bff1 + l * 8192, 1024);
    // x += (ff @ w_ff2 + b_ff2) * ls2 ; split-K x2 atomic (512 blocks)
    gemm_bt<64, 128, 1, 4, 2><<<dim3(8, 32, 2), 256, 0, stream>>>(
        ff_bf, 0, 2048, 4096, wff2Tl, 0, 2048, 4096, xout, 0, 0, 1024, 2048,
        1.f, bff2 + l * 1024, ls2 + l * 1024);
  }
}

// Round 4
// 1281.705 us; speedup vs baseline: 1.0388x; 1.0388x over previous
//
#include <hip/hip_runtime.h>
#include <cstdint>
#include <cstddef>

// ---------------------------------------------------------------- types
typedef __bf16 bf16_t;
typedef __bf16 bf16x8 __attribute__((ext_vector_type(8)));
typedef __bf16 bf16x4 __attribute__((ext_vector_type(4)));
typedef float  f32x4  __attribute__((ext_vector_type(4)));
typedef short  s16x4  __attribute__((ext_vector_type(4)));

#define DEV __device__ __forceinline__

static constexpr int   BATCH = 2;
static constexpr int   NTOK  = 1024;
static constexpr int   DIM   = 1024;
static constexpr int   MROWS = BATCH * NTOK;      // 2048 token rows
static constexpr float SCALE = 0.125f;            // 64^-0.5 (exact in bf16)

// ------------------------------------------------------- global->LDS DMA
DEV void load_lds16(const bf16_t* g, bf16_t* s) {
  __builtin_amdgcn_global_load_lds(
      (const __attribute__((address_space(1))) void*)g,
      (__attribute__((address_space(3))) void*)s, 16, 0, 0);
}

// ------------------------------------------------------------ reductions
DEV float wave_sum(float v) {
#pragma unroll
  for (int m = 1; m < 64; m <<= 1) v += __shfl_xor(v, m, 64);
  return v;
}
DEV float block_sum(float v, float* sb) {
  v = wave_sum(v);
  __syncthreads();
  if ((threadIdx.x & 63) == 0) sb[threadIdx.x >> 6] = v;
  __syncthreads();
  return sb[0] + sb[1] + sb[2] + sb[3];
}

// ------------------------------------------------------------------ GEMM
// C[M,N] = A[M,K] @ B[K,N], with B given transposed: BT[N][K] (row-major).
// Fragment layout (verified):
//   A frag:  A[m = lane&15][k = (lane>>4)*8 + j]   -> 8 contiguous bf16
//   B frag:  BT[n = lane&15][k = (lane>>4)*8 + j]  -> 8 contiguous bf16
//   C/D:     col = lane&15, row = (lane>>4)*4 + reg
// Batch via blockIdx.z: off = (z>>4)*s0 + (z&15)*s1.
// MODE 0: C(bf16) = acc * (col<1024 ? alpha : 1)        [qkv, q pre-scale]
// MODE 1: C(bf16) = acc + bias[col]
// MODE 2: C(f32) += (acc + bias[col]) * ls[col]         [residual rmw]
template <int BM, int BN, int WR, int WC, int MODE>
__global__ __launch_bounds__(256) void gemm_bt(
    const bf16_t* __restrict__ A, long sA0, long sA1, int lda,
    const bf16_t* __restrict__ B, long sB0, long sB1, int ldb,
    void* __restrict__ Cv, long sC0, long sC1, int ldc,
    int K, float alpha, const float* __restrict__ bias,
    const float* __restrict__ ls) {
  constexpr int TM = BM / WR / 16;
  constexpr int TN = BN / WC / 16;
  __shared__ __attribute__((aligned(16))) bf16_t As[BM * 32];
  __shared__ __attribute__((aligned(16))) bf16_t Bs[BN * 32];

  const int tid  = threadIdx.x;
  const int lane = tid & 63, wave = tid >> 6;
  const int z  = blockIdx.z;
  const int zh = z >> 4, zl = z & 15;
  A += (size_t)zh * sA0 + (size_t)zl * sA1;
  B += (size_t)zh * sB0 + (size_t)zl * sB1;

  const int m0 = blockIdx.y * BM, n0 = blockIdx.x * BN;
  const int wm = (wave / WC) * (BM / WR);
  const int wn = (wave % WC) * (BN / WC);
  const int fm = lane & 15, quad = lane >> 4;

  f32x4 acc[TM][TN] = {};

  for (int k0 = 0; k0 < K; k0 += 32) {
#pragma unroll
    for (int c = tid; c < BM * 4; c += 256) {
      const int row = c >> 2, kc = (c & 3) << 3;
      load_lds16(A + (size_t)(m0 + row) * lda + k0 + kc, &As[c * 8]);
    }
#pragma unroll
    for (int c = tid; c < BN * 4; c += 256) {
      const int row = c >> 2, kc = (c & 3) << 3;
      load_lds16(B + (size_t)(n0 + row) * ldb + k0 + kc, &Bs[c * 8]);
    }
    __syncthreads();

    bf16x8 af[TM], bfr[TN];
#pragma unroll
    for (int i = 0; i < TM; ++i)
      af[i] = *(const bf16x8*)&As[(wm + i * 16 + fm) * 32 + quad * 8];
#pragma unroll
    for (int j = 0; j < TN; ++j)
      bfr[j] = *(const bf16x8*)&Bs[(wn + j * 16 + fm) * 32 + quad * 8];
#pragma unroll
    for (int i = 0; i < TM; ++i)
#pragma unroll
      for (int j = 0; j < TN; ++j)
        acc[i][j] = __builtin_amdgcn_mfma_f32_16x16x32_bf16(af[i], bfr[j],
                                                            acc[i][j], 0, 0, 0);
    __syncthreads();
  }

  const size_t coff = (size_t)zh * sC0 + (size_t)zl * sC1;
#pragma unroll
  for (int i = 0; i < TM; ++i) {
#pragma unroll
    for (int j = 0; j < TN; ++j) {
      const int col  = n0 + wn + j * 16 + fm;
      const int rowb = m0 + wm + i * 16 + quad * 4;
#pragma unroll
      for (int r = 0; r < 4; ++r) {
        const float  v   = acc[i][j][r];
        const size_t idx = coff + (size_t)(rowb + r) * ldc + col;
        if constexpr (MODE == 0) {
          ((bf16_t*)Cv)[idx] = (bf16_t)(col < 1024 ? v * alpha : v);
        } else if constexpr (MODE == 1) {
          ((bf16_t*)Cv)[idx] = (bf16_t)(v + bias[col]);
        } else {
          float* C = (float*)Cv;
          C[idx]   = C[idx] + (v + bias[col]) * ls[col];
        }
      }
    }
  }
}

// ---------------------------------------------- fused ff1 + GEGLU GEMM
// ff[M,4096] = (h @ Wa + ba) * gelu(h @ Wg + bg)
// Wa = wff1T rows [0,4096), Wg = rows [4096,8192) (BT layout [8192][1024]).
// 128x64 tiles -> 1024 blocks (4/CU), 64-reg accum, m97-ratio inner loop.
template <int BM, int BN>
__global__ __launch_bounds__(256) void gemm_ff1_geglu(
    const bf16_t* __restrict__ A, int lda,
    const bf16_t* __restrict__ BT,           // [8192][1024]
    bf16_t* __restrict__ ff,                 // [M][4096]
    const float* __restrict__ bias,          // [8192]
    int K) {
  constexpr int WR = 2, WC = 2;
  constexpr int TM = BM / WR / 16;           // 4
  constexpr int TN = BN / WC / 16;           // 2
  __shared__ __attribute__((aligned(16))) bf16_t As[BM * 32];
  __shared__ __attribute__((aligned(16))) bf16_t Bas[BN * 32];
  __shared__ __attribute__((aligned(16))) bf16_t Bgs[BN * 32];

  const int tid  = threadIdx.x;
  const int lane = tid & 63, wave = tid >> 6;
  const int m0 = blockIdx.y * BM, n0 = blockIdx.x * BN;
  const int wm = (wave / WC) * (BM / WR);
  const int wn = (wave % WC) * (BN / WC);
  const int fm = lane & 15, quad = lane >> 4;

  const bf16_t* Ba = BT + (size_t)n0 * K;
  const bf16_t* Bg = BT + (size_t)(n0 + 4096) * K;

  f32x4 acca[TM][TN] = {}, accg[TM][TN] = {};

  for (int k0 = 0; k0 < K; k0 += 32) {
#pragma unroll
    for (int c = tid; c < BM * 4; c += 256) {
      const int row = c >> 2, kc = (c & 3) << 3;
      load_lds16(A + (size_t)(m0 + row) * lda + k0 + kc, &As[c * 8]);
    }
#pragma unroll
    for (int c = tid; c < BN * 4; c += 256) {
      const int row = c >> 2, kc = (c & 3) << 3;
      load_lds16(Ba + (size_t)row * K + k0 + kc, &Bas[c * 8]);
      load_lds16(Bg + (size_t)row * K + k0 + kc, &Bgs[c * 8]);
    }
    __syncthreads();

    bf16x8 af[TM], ba[TN], bg[TN];
#pragma unroll
    for (int i = 0; i < TM; ++i)
      af[i] = *(const bf16x8*)&As[(wm + i * 16 + fm) * 32 + quad * 8];
#pragma unroll
    for (int j = 0; j < TN; ++j) {
      ba[j] = *(const bf16x8*)&Bas[(wn + j * 16 + fm) * 32 + quad * 8];
      bg[j] = *(const bf16x8*)&Bgs[(wn + j * 16 + fm) * 32 + quad * 8];
    }
#pragma unroll
    for (int i = 0; i < TM; ++i)
#pragma unroll
      for (int j = 0; j < TN; ++j) {
        acca[i][j] = __builtin_amdgcn_mfma_f32_16x16x32_bf16(af[i], ba[j],
                                                             acca[i][j], 0, 0, 0);
        accg[i][j] = __builtin_amdgcn_mfma_f32_16x16x32_bf16(af[i], bg[j],
                                                             accg[i][j], 0, 0, 0);
      }
    __syncthreads();
  }

#pragma unroll
  for (int i = 0; i < TM; ++i) {
#pragma unroll
    for (int j = 0; j < TN; ++j) {
      const int col  = n0 + wn + j * 16 + fm;
      const int rowb = m0 + wm + i * 16 + quad * 4;
      const float ab = bias[col], gb = bias[col + 4096];
#pragma unroll
      for (int r = 0; r < 4; ++r) {
        const float a  = acca[i][j][r] + ab;
        const float g  = accg[i][j][r] + gb;
        const float ge = 0.5f * g * (1.f + erff(g * 0.70710678118654752f));
        ff[(size_t)(rowb + r) * 4096 + col] = (bf16_t)(a * ge);
      }
    }
  }
}

// --------------------------------------------------------- flash attention
// One block per (64-row Q tile, z = b*16+h). 4 waves, each owning 16 Q rows.
// Computes S^T = K @ Q^T (operand-swapped MFMA): C-layout gives
// col = query (lane&15), row = key token (quad*4+reg). That register layout
// IS the A-fragment layout of mfma_f32_16x16x16bf16_1k (K=16), so P feeds
// P@V directly from registers — no LDS round-trip for P.
// Q is pre-scaled by SCALE in the qkv GEMM epilogue.
__global__ __launch_bounds__(256) void flash_attn(
    const bf16_t* __restrict__ qkv,   // [2][1024][3072] (q cols pre-scaled)
    const bf16_t* __restrict__ vT,    // [32][64][1024]
    bf16_t* __restrict__ o) {         // [2][1024][1024] col = h*64+d
  constexpr int NT = 128;
  __shared__ __attribute__((aligned(16))) bf16_t Qs[2 * 64 * 32];   // 8 KB
  __shared__ __attribute__((aligned(16))) bf16_t Ks[2 * NT * 32];   // 16 KB
  __shared__ __attribute__((aligned(16))) bf16_t Vs[4 * 64 * 32];   // 16 KB

  const int tid = threadIdx.x, lane = tid & 63, wave = tid >> 6;
  const int fm = lane & 15, quad = lane >> 4;
  const int z = blockIdx.y, b = z >> 4, h = z & 15;
  const int q0 = blockIdx.x * 64;
  const bf16_t* qb  = qkv + (size_t)b * 1024 * 3072 + h * 64;
  const bf16_t* kb  = qb + 1024;
  const bf16_t* vtb = vT + (size_t)z * 64 * 1024;

  // stage Q tile: layout [kk(2)][row(64)][32]
  for (int c = tid; c < 512; c += 256) {
    const int kk = c >> 8, rr = (c >> 2) & 63, ii = c & 3;
    load_lds16(qb + (size_t)(q0 + rr) * 3072 + kk * 32 + ii * 8, &Qs[c * 8]);
  }
  __syncthreads();
  bf16x8 qf[2];
  qf[0] = *(const bf16x8*)&Qs[(wave * 16 + fm) * 32 + quad * 8];
  qf[1] = *(const bf16x8*)&Qs[64 * 32 + (wave * 16 + fm) * 32 + quad * 8];

  float mr = -1e30f, lr = 0.f;
  f32x4 oacc[4] = {};

  for (int kv0 = 0; kv0 < 1024; kv0 += NT) {
    __syncthreads();  // all waves done reading previous K/V tiles
    // K tile [kk(2)][tok(128)][32]
    for (int c = tid; c < NT * 8; c += 256) {
      const int kk = c >> 9, rr = (c >> 2) & 127, ii = c & 3;
      load_lds16(kb + (size_t)(kv0 + rr) * 3072 + kk * 32 + ii * 8, &Ks[c * 8]);
    }
    // V^T tile [tc(4)][d(64)][32]
    for (int c = tid; c < 1024; c += 256) {
      const int tc = c >> 8, rr = (c >> 2) & 63, ii = c & 3;
      load_lds16(vtb + (size_t)rr * 1024 + kv0 + tc * 32 + ii * 8, &Vs[c * 8]);
    }
    __syncthreads();

    // S^T tiles: st[nt] holds S[query = lane&15][j = nt*16 + quad*4 + r]
    f32x4 st[8];
#pragma unroll
    for (int nt = 0; nt < 8; ++nt) {
      st[nt] = (f32x4){0.f, 0.f, 0.f, 0.f};
#pragma unroll
      for (int kk = 0; kk < 2; ++kk) {
        const bf16x8 kf =
            *(const bf16x8*)&Ks[kk * NT * 32 + (nt * 16 + fm) * 32 + quad * 8];
        st[nt] = __builtin_amdgcn_mfma_f32_16x16x32_bf16(kf, qf[kk], st[nt],
                                                         0, 0, 0);
      }
    }
    // online softmax: this lane owns one query row (lane&15), 32 j's;
    // full row spread across the 4 quads -> xor-16/32 reductions.
    float mx = st[0][0];
#pragma unroll
    for (int nt = 0; nt < 8; ++nt)
#pragma unroll
      for (int r = 0; r < 4; ++r) mx = fmaxf(mx, st[nt][r]);
    mx = fmaxf(mx, __shfl_xor(mx, 16, 64));
    mx = fmaxf(mx, __shfl_xor(mx, 32, 64));
    const float mn = fmaxf(mr, mx);
    const float al = __expf(mr - mn);
    mr = mn;
    float ps = 0.f;
    s16x4 pf[8];
#pragma unroll
    for (int nt = 0; nt < 8; ++nt) {
      bf16x4 pv;
#pragma unroll
      for (int r = 0; r < 4; ++r) {
        const float p = __expf(st[nt][r] - mn);
        ps += p;
        pv[r] = (bf16_t)p;
      }
      pf[nt] = __builtin_bit_cast(s16x4, pv);
    }
    ps += __shfl_xor(ps, 16, 64);
    ps += __shfl_xor(ps, 32, 64);
    lr = lr * al + ps;
    // rescale O: O rows are quad*4+r -> fetch that row's alpha via shuffle
    float alr[4];
#pragma unroll
    for (int r = 0; r < 4; ++r) alr[r] = __shfl(al, quad * 4 + r, 64);
#pragma unroll
    for (int t = 0; t < 4; ++t)
#pragma unroll
      for (int r = 0; r < 4; ++r) oacc[t][r] *= alr[r];
    // O += P @ V  (K=16 MFMA; P straight from registers)
#pragma unroll
    for (int nt = 0; nt < 8; ++nt) {
      const int tok = nt * 16 + quad * 4;
      const int tc = tok >> 5, tin = tok & 31;
#pragma unroll
      for (int t = 0; t < 4; ++t) {
        const bf16x4 vv =
            *(const bf16x4*)&Vs[tc * 2048 + (t * 16 + fm) * 32 + tin];
        oacc[t] = __builtin_amdgcn_mfma_f32_16x16x16bf16_1k(
            pf[nt], __builtin_bit_cast(s16x4, vv), oacc[t], 0, 0, 0);
      }
    }
  }

  // epilogue: normalize and store (C layout: row = quad*4+r, col = t*16+fm)
  float linv[4];
#pragma unroll
  for (int r = 0; r < 4; ++r) linv[r] = 1.f / __shfl(lr, quad * 4 + r, 64);
  const size_t orow0 = (size_t)b * 1024 + q0 + wave * 16 + quad * 4;
#pragma unroll
  for (int t = 0; t < 4; ++t) {
    const int col = h * 64 + t * 16 + fm;
#pragma unroll
    for (int r = 0; r < 4; ++r)
      o[(orow0 + r) * 1024 + col] = (bf16_t)(oacc[t][r] * linv[r]);
  }
}

// ------------------------------------------------- weight transpose+cast
// W[K][N] fp32 -> WT[N][K] bf16, all DEPTH layers via blockIdx.z.
__global__ __launch_bounds__(256) void transpose_w(const float* __restrict__ W,
                                                   bf16_t* __restrict__ WT,
                                                   int K, int N) {
  __shared__ float t[32][33];
  W  += (size_t)blockIdx.z * K * N;
  WT += (size_t)blockIdx.z * K * N;
  const int n0 = blockIdx.x * 32, k0 = blockIdx.y * 32;
  const int tx = threadIdx.x & 31, ty = threadIdx.x >> 5;
#pragma unroll
  for (int s = 0; s < 4; ++s)
    t[ty + 8 * s][tx] = W[(size_t)(k0 + ty + 8 * s) * N + n0 + tx];
  __syncthreads();
#pragma unroll
  for (int s = 0; s < 4; ++s)
    WT[(size_t)(n0 + ty + 8 * s) * K + k0 + tx] = (bf16_t)t[tx][ty + 8 * s];
}

// ----------------------------------------------------- V transpose (bf16)
// qkv[b*1024+tok][2048 + h*64 + d] -> vT[z=b*16+h][d][tok]
__global__ __launch_bounds__(256) void transpose_v(const bf16_t* __restrict__ qkv,
                                                   bf16_t* __restrict__ vT) {
  __shared__ bf16_t t[32][33];
  const int z = blockIdx.z, b = z >> 4, h = z & 15;
  const int d0 = blockIdx.y * 32, n0 = blockIdx.x * 32;
  const int tx = threadIdx.x & 31, ty = threadIdx.x >> 5;
  const bf16_t* src = qkv + (size_t)b * NTOK * 3072 + 2048 + h * 64;
#pragma unroll
  for (int s = 0; s < 4; ++s)
    t[ty + 8 * s][tx] = src[(size_t)(n0 + ty + 8 * s) * 3072 + d0 + tx];
  __syncthreads();
  bf16_t* dst = vT + (size_t)z * 64 * NTOK;
#pragma unroll
  for (int s = 0; s < 4; ++s)
    dst[(size_t)(d0 + ty + 8 * s) * NTOK + n0 + tx] = t[tx][ty + 8 * s];
}

// -------------------------------------------------------------- layernorm
__global__ __launch_bounds__(256) void ln_kernel(const float* __restrict__ x,
                                                 const float* __restrict__ w,
                                                 const float* __restrict__ b,
                                                 bf16_t* __restrict__ out) {
  __shared__ float sb[4];
  const int row = blockIdx.x, tid = threadIdx.x;
  const float4 v = ((const float4*)(x + (size_t)row * DIM))[tid];
  float s = v.x + v.y + v.z + v.w;
  s = block_sum(s, sb);
  const float mu = s * (1.f / DIM);
  const float dx = v.x - mu, dy = v.y - mu, dz = v.z - mu, dw = v.w - mu;
  float q = dx * dx + dy * dy + dz * dz + dw * dw;
  q = block_sum(q, sb);
  const float rstd = rsqrtf(q * (1.f / DIM) + 1e-5f);
  const float4 wv = ((const float4*)w)[tid];
  const float4 bv = ((const float4*)b)[tid];
  bf16x4 o;
  o[0] = (bf16_t)(dx * rstd * wv.x + bv.x);
  o[1] = (bf16_t)(dy * rstd * wv.y + bv.y);
  o[2] = (bf16_t)(dz * rstd * wv.z + bv.z);
  o[3] = (bf16_t)(dw * rstd * wv.w + bv.w);
  ((bf16x4*)(out + (size_t)row * DIM))[tid] = o;
}

// ------------------------------------------------------------------ launch
extern "C" void kernel_launch(void* const* d_in, const int* in_sizes, int n_in,
                              void* d_out, int out_size, void* d_ws,
                              size_t ws_size, hipStream_t stream) {
  const float* x_in = (const float*)d_in[0];
  const float* ln1w = (const float*)d_in[1];
  const float* ln1b = (const float*)d_in[2];
  const float* wqkv = (const float*)d_in[3];
  const float* wout = (const float*)d_in[4];
  const float* bout = (const float*)d_in[5];
  const float* ls1  = (const float*)d_in[6];
  const float* ln2w = (const float*)d_in[7];
  const float* ln2b = (const float*)d_in[8];
  const float* wff1 = (const float*)d_in[9];
  const float* bff1 = (const float*)d_in[10];
  const float* wff2 = (const float*)d_in[11];
  const float* bff2 = (const float*)d_in[12];
  const float* ls2  = (const float*)d_in[13];
  float*       xout = (float*)d_out;

  // -------- workspace carve-up (~176 MB)
  char*   ws     = (char*)d_ws;
  bf16_t* wqkvT  = (bf16_t*)ws; ws += (size_t)4 * 3072 * 1024 * 2;  // 25.2 MB
  bf16_t* woutT  = (bf16_t*)ws; ws += (size_t)4 * 1024 * 1024 * 2;  //  8.4 MB
  bf16_t* wff1T  = (bf16_t*)ws; ws += (size_t)4 * 8192 * 1024 * 2;  // 67.1 MB
  bf16_t* wff2T  = (bf16_t*)ws; ws += (size_t)4 * 1024 * 4096 * 2;  // 33.6 MB
  bf16_t* h_bf   = (bf16_t*)ws; ws += (size_t)MROWS * 1024 * 2;     //  4.2 MB
  bf16_t* qkv_bf = (bf16_t*)ws; ws += (size_t)MROWS * 3072 * 2;     // 12.6 MB
  bf16_t* o_bf   = (bf16_t*)ws; ws += (size_t)MROWS * 1024 * 2;     //  4.2 MB
  bf16_t* vT     = (bf16_t*)ws; ws += (size_t)32 * 64 * 1024 * 2;   //  4.2 MB
  bf16_t* ff_bf  = (bf16_t*)ws; ws += (size_t)MROWS * 4096 * 2;     // 16.8 MB
  if (ws_size < (size_t)(ws - (char*)d_ws)) return;  // visible fail

  hipMemcpyAsync(xout, x_in, (size_t)MROWS * DIM * 4,
                 hipMemcpyDeviceToDevice, stream);

  // ---- all weight transposes up front (all 4 layers per launch)
  transpose_w<<<dim3(96, 32, 4), 256, 0, stream>>>(wqkv, wqkvT, 1024, 3072);
  transpose_w<<<dim3(32, 32, 4), 256, 0, stream>>>(wout, woutT, 1024, 1024);
  transpose_w<<<dim3(256, 32, 4), 256, 0, stream>>>(wff1, wff1T, 1024, 8192);
  transpose_w<<<dim3(32, 128, 4), 256, 0, stream>>>(wff2, wff2T, 4096, 1024);

  for (int l = 0; l < 4; ++l) {
    const bf16_t* wqkvTl = wqkvT + (size_t)l * 3072 * 1024;
    const bf16_t* woutTl = woutT + (size_t)l * 1024 * 1024;
    const bf16_t* wff1Tl = wff1T + (size_t)l * 8192 * 1024;
    const bf16_t* wff2Tl = wff2T + (size_t)l * 4096 * 1024;

    // ---- attention
    ln_kernel<<<MROWS, 256, 0, stream>>>(xout, ln1w + l * 1024,
                                         ln1b + l * 1024, h_bf);
    // qkv = h @ wqkv ; q columns pre-scaled by SCALE. 768 blocks (3/CU).
    gemm_bt<64, 128, 1, 4, 0><<<dim3(24, 32, 1), 256, 0, stream>>>(
        h_bf, 0, 0, 1024, wqkvTl, 0, 0, 1024, qkv_bf, 0, 0, 3072, 1024,
        SCALE, nullptr, nullptr);
    transpose_v<<<dim3(32, 2, 32), 256, 0, stream>>>(qkv_bf, vT);
    flash_attn<<<dim3(16, 32), 256, 0, stream>>>(qkv_bf, vT, o_bf);
    // x += (o @ w_out + b_out) * ls1   (plain rmw, 256 blocks)
    gemm_bt<64, 128, 1, 4, 2><<<dim3(8, 32, 1), 256, 0, stream>>>(
        o_bf, 0, 0, 1024, woutTl, 0, 0, 1024, xout, 0, 0, 1024, 1024,
        1.f, bout + l * 1024, ls1 + l * 1024);

    // ---- feedforward
    ln_kernel<<<MROWS, 256, 0, stream>>>(xout, ln2w + l * 1024,
                                         ln2b + l * 1024, h_bf);
    // fused ff1 + geglu (1024 blocks, 128x64 tiles)
    gemm_ff1_geglu<128, 64><<<dim3(64, 16), 256, 0, stream>>>(
        h_bf, 1024, wff1Tl, ff_bf, bff1 + l * 8192, 1024);
    // x += (ff @ w_ff2 + b_ff2) * ls2  (plain rmw, 256 blocks)
    gemm_bt<64, 128, 1, 4, 2><<<dim3(8, 32, 1), 256, 0, stream>>>(
        ff_bf, 0, 0, 4096, wff2Tl, 0, 0, 4096, xout, 0, 0, 1024, 4096,
        1.f, bff2 + l * 1024, ls2 + l * 1024);
  }
}